// Round 11
// baseline (148.069 us; speedup 1.0000x reference)
//
#include <hip/hip_runtime.h>
#include <float.h>

#define NA_TOTAL 8400
#define BSZ 32
#define NMAX 64
#define BG_IDX 80
#define NTILE 33   // ceil(8400/256)

// -------- IoU exactly mirroring the reference formula (no fp contraction) ----
__device__ __forceinline__ float iou_pair(float ax1, float ay1, float ax2, float ay2,
                                          float bx1, float by1, float bx2, float by2) {
#pragma clang fp contract(off)
  float ltx = fmaxf(ax1, bx1);
  float lty = fmaxf(ay1, by1);
  float rbx = fminf(ax2, bx2);
  float rby = fminf(ay2, by2);
  float w = fmaxf(rbx - ltx, 0.0f);
  float h = fmaxf(rby - lty, 0.0f);
  float inter = w * h;
  float a1 = (ax2 - ax1) * (ay2 - ay1);
  float a2 = (bx2 - bx1) * (by2 - by1);
  return inter / (a1 + a2 - inter + 1e-9f);
}

// ONE dispatch. Grid (33 tiles, 32 images), 256 threads (round-5's proven
// block shape — round-10 lesson: 1024-thread blocks spilled to scratch).
// Phase A: each of the 4 waves redundantly runs stage-1 (identical math to
//   the passing rounds) for the gts of image b whose 5x5 candidate windows
//   can overlap this block's 256-anchor tile. Conservative exact prune:
//   all 25 candidates of level lv lie in [startA+wy0*n+wx0,
//   startA+(wy0+4)*n+wx0+4]; if that span misses the tile, the gt cannot
//   contribute here. Results go to LDS plist (init -1).
// Phase B: scatter plist -> per-anchor 64-bit gt mask (LDS atomics).
// Phase C: resolve (popcount / ctz / rare 64-IoU argmax), write lab/box/fgm.
// Phase D: coalesced 80-wide score streaming.
__global__ __launch_bounds__(256) void fused_kernel(
    const float* __restrict__ anchors,   // [8400,4]
    const float* __restrict__ gt_boxes,  // [32,64,4]
    const float* __restrict__ mask_gt,   // [32,64]
    const int* __restrict__ labels,      // [32,64]
    const float* __restrict__ pred,      // [32,8400,4]
    float* __restrict__ out_lab,         // [32,8400]
    float* __restrict__ out_box,         // [32,8400,4]
    float4* __restrict__ out_sco4,       // [32*8400*20] float4 view
    float* __restrict__ out_fgm) {       // [32,8400]
#pragma clang fp contract(off)
  const int b = blockIdx.y;
  const int A0 = blockIdx.x * 256;
  const int tid = threadIdx.x;
  const int lane = tid & 63;
  const int wv = tid >> 6;   // 0..3

  __shared__ int plist[NMAX * 27];
  __shared__ unsigned mLo[256];
  __shared__ unsigned mHi[256];
  __shared__ float4 gts[64];
  __shared__ int labs[64];
  __shared__ int lab_s[256];
  __shared__ float im_s[256];

  if (tid < 64) {
    gts[tid] = ((const float4*)gt_boxes)[b * 64 + tid];
    labs[tid] = labels[b * 64 + tid];
  }
  for (int i = tid; i < NMAX * 27; i += 256) plist[i] = -1;
  mLo[tid] = 0u;
  mHi[tid] = 0u;
  __syncthreads();

  // ---- Phase A: wave wv handles gts {wv, wv+4, ...} with window-tile prune --
  for (int g = wv; g < NMAX; g += 4) {
    const int t = b * 64 + g;
    if (mask_gt[t] <= 0.0f) continue;  // wave-uniform

    const float4 gtb = ((const float4*)gt_boxes)[t];
    const float gx1 = gtb.x, gy1 = gtb.y, gx2 = gtb.z, gy2 = gtb.w;
    const float gcx = 0.5f * (gx1 + gx2);
    const float gcy = 0.5f * (gy1 + gy2);

    int wx0s[3], wy0s[3];
    bool qual = false;
#pragma unroll
    for (int lv = 0; lv < 3; ++lv) {
      const int strd = (lv == 0) ? 8 : (lv == 1) ? 16 : 32;
      const int n = (lv == 0) ? 80 : (lv == 1) ? 40 : 20;
      const int startA = (lv == 0) ? 0 : (lv == 1) ? 6400 : 8000;
      const float inv = 1.0f / (float)strd;
      int ix0 = (int)floorf(gcx * inv);
      int iy0 = (int)floorf(gcy * inv);
      ix0 = min(max(ix0, 0), n - 1);
      iy0 = min(max(iy0, 0), n - 1);
      int wx0 = min(max(ix0 - 2, 0), n - 5);
      int wy0 = min(max(iy0 - 2, 0), n - 5);
      wx0s[lv] = wx0;
      wy0s[lv] = wy0;
      int lo = startA + wy0 * n + wx0;
      int hi = startA + (wy0 + 4) * n + wx0 + 4;
      qual = qual || ((hi >= A0) && (lo < A0 + 256));
    }
    if (!qual) continue;  // wave-uniform; gt can't touch this tile

    float io_arr[3];
    int aidx[3];
    bool sel_arr[3];
    unsigned long long bal[3];

#pragma unroll
    for (int lv = 0; lv < 3; ++lv) {
      const int n = (lv == 0) ? 80 : (lv == 1) ? 40 : 20;
      const int startA = (lv == 0) ? 0 : (lv == 1) ? 6400 : 8000;
      const int wx0 = wx0s[lv], wy0 = wy0s[lv];

      int a = startA + (wy0 + lane / 5) * n + (wx0 + lane % 5);
      aidx[lv] = a;
      float d = FLT_MAX;
      float iov = 0.0f;
      if (lane < 25) {
        float4 ab = ((const float4*)anchors)[a];
        float acx = 0.5f * (ab.x + ab.z);
        float acy = 0.5f * (ab.y + ab.w);
        float dx = gcx - acx;
        float dy = gcy - acy;
        d = sqrtf(dx * dx + dy * dy);
        iov = iou_pair(gx1, gy1, gx2, gy2, ab.x, ab.y, ab.z, ab.w);
      }
      io_arr[lv] = iov;

      // rank via all-to-all compare over lanes 0..24 ((dist, idx) lex order)
      int cnt = 0;
      for (int j = 0; j < 25; ++j) {
        float dj = __shfl(d, j);
        cnt += (int)((dj < d) | ((dj == d) & (j < lane)));
      }
      bool sel = (lane < 25) && (cnt < 9);
      sel_arr[lv] = sel;
      bal[lv] = __ballot(sel);
    }

    // thr = mean + std (ddof=1), double two-pass, slot order — instruction-
    // identical to all passing rounds.
    double s = 0.0;
#pragma unroll
    for (int lv = 0; lv < 3; ++lv)
      for (int j = 0; j < 25; ++j) {
        float v = __shfl(io_arr[lv], j);
        s += ((bal[lv] >> j) & 1ull) ? (double)v : 0.0;
      }
    double mean = s / 27.0;
    double s2 = 0.0;
#pragma unroll
    for (int lv = 0; lv < 3; ++lv)
      for (int j = 0; j < 25; ++j) {
        float v = __shfl(io_arr[lv], j);
        double dd = (double)v - mean;
        s2 += ((bal[lv] >> j) & 1ull) ? dd * dd : 0.0;
      }
    float thr = (float)(mean + sqrt(s2 / 26.0));

#pragma unroll
    for (int lv = 0; lv < 3; ++lv) {
      if (sel_arr[lv]) {
        int rank = (int)__popcll(bal[lv] & ((1ull << lane) - 1ull));
        int val = -1;
        if (io_arr[lv] > thr) {
          int a = aidx[lv];
          float4 ab = ((const float4*)anchors)[a];
          float acx = 0.5f * (ab.x + ab.z);
          float acy = 0.5f * (ab.y + ab.w);
          float d_in = fminf(fminf(acx - gx1, acy - gy1),
                             fminf(gx2 - acx, gy2 - acy));
          if (d_in > 1e-9f) val = a;
        }
        plist[g * 27 + lv * 9 + rank] = val;
      }
    }
  }
  __syncthreads();

  // ---- Phase B: scatter candidates into per-anchor gt bitmask (LDS) --------
  for (int i = tid; i < NMAX * 27; i += 256) {
    int av = plist[i];
    if (av >= A0 && av < A0 + 256) {
      int g = i / 27;
      int la = av - A0;
      if (g < 32) atomicOr(&mLo[la], 1u << g);
      else        atomicOr(&mHi[la], 1u << (g - 32));
    }
  }
  __syncthreads();

  // ---- Phase C: resolve per anchor + write lab/box/fgm ---------------------
  const int a = A0 + tid;
  const bool valid = a < NA_TOTAL;
  int lab = BG_IDX;
  float im = 0.0f;
  if (valid) {
    const size_t idx = (size_t)b * NA_TOTAL + a;
    unsigned long long bits =
        (unsigned long long)mLo[tid] | ((unsigned long long)mHi[tid] << 32);
    int fg = __popcll(bits);
    bool pos = fg > 0;
    int target = 0;
    if (fg == 1) {
      target = __builtin_ctzll(bits);
    } else if (fg > 1) {
      // multi-assignment -> argmax_g IoU(gt[g], anchor), first-max tie-break
      float4 ab = ((const float4*)anchors)[a];
      float best = -1.0f;
      int bi = 0;
      for (int g2 = 0; g2 < 64; ++g2) {
        float4 gb = gts[g2];
        float v = iou_pair(gb.x, gb.y, gb.z, gb.w, ab.x, ab.y, ab.z, ab.w);
        if (v > best) { best = v; bi = g2; }
      }
      target = bi;
    }
    lab = pos ? labs[target] : BG_IDX;
    out_lab[idx] = (float)lab;
    float4 tb = gts[target];  // background -> gt[0], matching reference
    ((float4*)out_box)[idx] = tb;
    out_fgm[idx] = pos ? 1.0f : 0.0f;
    if (pos) {
      float4 pb = ((const float4*)pred)[idx];
      im = iou_pair(tb.x, tb.y, tb.z, tb.w, pb.x, pb.y, pb.z, pb.w);
    }
  }
  lab_s[tid] = lab;
  im_s[tid] = im;
  __syncthreads();

  // ---- Phase D: coalesced score streaming ----------------------------------
  const int ntile = min(NA_TOTAL - A0, 256);
  const int nval = ntile * 20;
  const size_t base = (size_t)b * NA_TOTAL * 20 + (size_t)A0 * 20;
  for (int k = tid; k < nval; k += 256) {
    int la = k / 20;
    int q = k - la * 20;
    int lb = lab_s[la];
    float v_im = im_s[la];
    int c0 = q * 4;
    float4 v;
    v.x = (lb == c0 + 0) ? v_im : 0.0f;
    v.y = (lb == c0 + 1) ? v_im : 0.0f;
    v.z = (lb == c0 + 2) ? v_im : 0.0f;
    v.w = (lb == c0 + 3) ? v_im : 0.0f;
    out_sco4[base + k] = v;
  }
}

extern "C" void kernel_launch(void* const* d_in, const int* in_sizes, int n_in,
                              void* d_out, int out_size, void* d_ws, size_t ws_size,
                              hipStream_t stream) {
  const float* anchors = (const float*)d_in[0];
  // d_in[1] = num_anchors_list (compile-time constants here)
  const int* labels = (const int*)d_in[2];
  const float* gt_boxes = (const float*)d_in[3];
  const float* mask_gt = (const float*)d_in[4];
  const float* pred = (const float*)d_in[5];

  float* out = (float*)d_out;
  float* out_lab = out;                                    // 32*8400
  float* out_box = out + (size_t)BSZ * NA_TOTAL;           // 32*8400*4
  float* out_sco = out + (size_t)BSZ * NA_TOTAL * 5;       // 32*8400*80
  float* out_fgm = out + (size_t)BSZ * NA_TOTAL * 85;      // 32*8400

  dim3 grid(NTILE, BSZ);  // 33x32 = 1056 blocks, 256 threads
  fused_kernel<<<grid, 256, 0, stream>>>(anchors, gt_boxes, mask_gt, labels,
                                         pred, out_lab, out_box,
                                         (float4*)out_sco, out_fgm);
}

// Round 12
// 30.075 us; speedup vs baseline: 4.9234x; 4.9234x over previous
//
#include <hip/hip_runtime.h>
#include <float.h>

#define NA_TOTAL 8400
#define BSZ 32
#define NMAX 64
#define BG_IDX 80

// -------- IoU exactly mirroring the reference formula (no fp contraction) ----
__device__ __forceinline__ float iou_pair(float ax1, float ay1, float ax2, float ay2,
                                          float bx1, float by1, float bx2, float by2) {
#pragma clang fp contract(off)
  float ltx = fmaxf(ax1, bx1);
  float lty = fmaxf(ay1, by1);
  float rbx = fminf(ax2, bx2);
  float rby = fminf(ay2, by2);
  float w = fmaxf(rbx - ltx, 0.0f);
  float h = fmaxf(rby - lty, 0.0f);
  float inter = w * h;
  float a1 = (ax2 - ax1) * (ay2 - ay1);
  float a2 = (bx2 - bx1) * (by2 - by1);
  return inter / (a1 + a2 - inter + 1e-9f);
}

// -------- Stage 1: ONE WAVE per (b,g). Lanes 0..24 own the 5x5 window slots.
// Output: pos_list[b][g][27] = anchor index if that candidate is positive
// (top-9 by (dist,idx), iou>thr, center strictly inside gt) else -1.
// Round-11 lesson: the per-gt serial chain dominates this kernel's wall time.
// mean/std now use a 64-lane f64 butterfly (chain ~25 f64 ops instead of ~300
// sequential adds). f64 accumulation of f32 summands is order-insensitive to
// ~1e-14 relative; thr is cast to f32 (6e-8 granularity) -> no selection flip.
__global__ __launch_bounds__(256) void stage1_kernel(
    const float* __restrict__ anchors,   // [8400,4]
    const float* __restrict__ gt_boxes,  // [32,64,4]
    const float* __restrict__ mask_gt,   // [32,64]
    int* __restrict__ pos_list) {        // [32*64*27]
#pragma clang fp contract(off)
  const int lane = threadIdx.x & 63;
  const int wid = threadIdx.x >> 6;            // 4 waves per block
  const int t = blockIdx.x * 4 + wid;          // (b,g) flat, wave-uniform

  if (mask_gt[t] <= 0.0f) {  // wave-uniform branch
    if (lane < 27) pos_list[t * 27 + lane] = -1;
    return;
  }

  const float4 gtb = ((const float4*)gt_boxes)[t];
  const float gx1 = gtb.x, gy1 = gtb.y, gx2 = gtb.z, gy2 = gtb.w;
  const float gcx = 0.5f * (gx1 + gx2);
  const float gcy = 0.5f * (gy1 + gy2);

  float io_arr[3];                  // this lane's candidate IoU per level
  int aidx[3];                      // this lane's anchor index per level
  bool sel_arr[3];                  // selected in top-9?
  unsigned long long bal[3];        // ballot of selected lanes per level

#pragma unroll
  for (int lv = 0; lv < 3; ++lv) {
    const int strd = (lv == 0) ? 8 : (lv == 1) ? 16 : 32;
    const int n = (lv == 0) ? 80 : (lv == 1) ? 40 : 20;
    const int startA = (lv == 0) ? 0 : (lv == 1) ? 6400 : 8000;
    const float inv = 1.0f / (float)strd;

    int ix0 = (int)floorf(gcx * inv);
    int iy0 = (int)floorf(gcy * inv);
    ix0 = min(max(ix0, 0), n - 1);
    iy0 = min(max(iy0, 0), n - 1);
    int wx0 = min(max(ix0 - 2, 0), n - 5);
    int wy0 = min(max(iy0 - 2, 0), n - 5);

    // lane i (i<25) owns window slot i (slot order = increasing anchor index)
    int a = startA + (wy0 + lane / 5) * n + (wx0 + lane % 5);
    aidx[lv] = a;
    float d = FLT_MAX;
    float iov = 0.0f;
    if (lane < 25) {
      float4 ab = ((const float4*)anchors)[a];
      float acx = 0.5f * (ab.x + ab.z);
      float acy = 0.5f * (ab.y + ab.w);
      float dx = gcx - acx;
      float dy = gcy - acy;
      d = sqrtf(dx * dx + dy * dy);
      iov = iou_pair(gx1, gy1, gx2, gy2, ab.x, ab.y, ab.z, ab.w);
    }
    io_arr[lv] = iov;

    // rank via all-to-all compare over lanes 0..24 ((dist, idx) lex order)
    int cnt = 0;
    for (int j = 0; j < 25; ++j) {
      float dj = __shfl(d, j);
      cnt += (int)((dj < d) | ((dj == d) & (j < lane)));
    }
    bool sel = (lane < 25) && (cnt < 9);
    sel_arr[lv] = sel;
    bal[lv] = __ballot(sel);
  }

  // thr = mean + std (ddof=1), f64 two-pass via 64-lane butterfly reduction.
  double local = 0.0;
#pragma unroll
  for (int lv = 0; lv < 3; ++lv)
    local += sel_arr[lv] ? (double)io_arr[lv] : 0.0;   // lanes>=25: sel=false
#pragma unroll
  for (int off = 32; off > 0; off >>= 1)
    local += __shfl_xor(local, off);
  double mean = local / 27.0;

  double l2 = 0.0;
#pragma unroll
  for (int lv = 0; lv < 3; ++lv) {
    double dd = (double)io_arr[lv] - mean;
    l2 += sel_arr[lv] ? dd * dd : 0.0;
  }
#pragma unroll
  for (int off = 32; off > 0; off >>= 1)
    l2 += __shfl_xor(l2, off);
  float thr = (float)(mean + sqrt(l2 / 26.0));

  // emit: each selected lane writes its entry (exactly 9 per level -> 27 total)
#pragma unroll
  for (int lv = 0; lv < 3; ++lv) {
    if (sel_arr[lv]) {
      int rank = (int)__popcll(bal[lv] & ((1ull << lane) - 1ull));
      int val = -1;
      if (io_arr[lv] > thr) {
        int a = aidx[lv];
        float4 ab = ((const float4*)anchors)[a];
        float acx = 0.5f * (ab.x + ab.z);
        float acy = 0.5f * (ab.y + ab.w);
        float d_in = fminf(fminf(acx - gx1, acy - gy1), fminf(gx2 - acx, gy2 - acy));
        if (d_in > 1e-9f) val = a;
      }
      pos_list[t * 27 + lv * 9 + rank] = val;
    }
  }
}

// -------- Stage 2 (fused): per (b, 256-anchor tile). Scatter pos_list into a
// per-anchor 64-bit gt mask in LDS, resolve assignment, write ALL outputs
// including the coalesced 80-wide score rows. (Byte-identical to round 5/9.)
__global__ __launch_bounds__(256) void stage2_kernel(
    const float* __restrict__ anchors,   // [8400,4]
    const float* __restrict__ gt_boxes,  // [32,64,4]
    const int* __restrict__ labels,      // [32,64]
    const float* __restrict__ pred,      // [32,8400,4]
    const int* __restrict__ pos_list,    // [32*64*27]
    float* __restrict__ out_lab,   // [32,8400]
    float* __restrict__ out_box,   // [32,8400,4]
    float4* __restrict__ out_sco4, // [32*8400*20] float4 view of scores
    float* __restrict__ out_fgm) { // [32,8400]
#pragma clang fp contract(off)
  const int b = blockIdx.y;
  const int A0 = blockIdx.x * 256;
  const int tid = threadIdx.x;
  const int a = A0 + tid;

  __shared__ float4 gts[64];
  __shared__ int labs[64];
  __shared__ unsigned mLo[256];
  __shared__ unsigned mHi[256];
  __shared__ int plist[64 * 27];
  __shared__ int lab_s[256];
  __shared__ float im_s[256];

  if (tid < 64) {
    gts[tid] = ((const float4*)gt_boxes)[b * 64 + tid];
    labs[tid] = labels[b * 64 + tid];
  }
  mLo[tid] = 0u;
  mHi[tid] = 0u;
  for (int i = tid; i < 64 * 27; i += 256) plist[i] = pos_list[b * 64 * 27 + i];
  __syncthreads();

  // scatter: entry i belongs to gt g=i/27; set bit g on its anchor (if in tile)
  for (int i = tid; i < 64 * 27; i += 256) {
    int av = plist[i];
    if (av >= A0 && av < A0 + 256) {
      int g = i / 27;
      int la = av - A0;
      if (g < 32) atomicOr(&mLo[la], 1u << g);
      else        atomicOr(&mHi[la], 1u << (g - 32));
    }
  }
  __syncthreads();

  const bool valid = a < NA_TOTAL;
  int lab = BG_IDX;
  float im = 0.0f;
  if (valid) {
    unsigned long long bits =
        (unsigned long long)mLo[tid] | ((unsigned long long)mHi[tid] << 32);
    int fg = __popcll(bits);
    bool pos = fg > 0;
    int target = 0;
    if (fg == 1) {
      target = __builtin_ctzll(bits);
    } else if (fg > 1) {
      // multi-assignment -> argmax_g IoU(gt[g], anchor), first-max tie-break
      float4 ab = ((const float4*)anchors)[a];
      float best = -1.0f;
      int bi = 0;
      for (int g2 = 0; g2 < 64; ++g2) {
        float4 gb = gts[g2];
        float v = iou_pair(gb.x, gb.y, gb.z, gb.w, ab.x, ab.y, ab.z, ab.w);
        if (v > best) { best = v; bi = g2; }
      }
      target = bi;
    }
    lab = pos ? labs[target] : BG_IDX;
    const size_t idx = (size_t)b * NA_TOTAL + a;
    out_lab[idx] = (float)lab;
    float4 tb = gts[target];  // background -> gt[0], matching reference
    ((float4*)out_box)[idx] = tb;
    out_fgm[idx] = pos ? 1.0f : 0.0f;
    if (pos) {
      float4 pb = ((const float4*)pred)[idx];
      im = iou_pair(tb.x, tb.y, tb.z, tb.w, pb.x, pb.y, pb.z, pb.w);
    }
  }
  lab_s[tid] = lab;
  im_s[tid] = im;
  __syncthreads();

  // coalesced score write: float4 index k covers (local anchor k/20, quad k%20)
  const int ntile = min(NA_TOTAL - A0, 256);
  const int nval = ntile * 20;
  const size_t base = (size_t)b * NA_TOTAL * 20 + (size_t)A0 * 20;
  for (int k = tid; k < nval; k += 256) {
    int la = k / 20;
    int q = k - la * 20;
    int lb = lab_s[la];
    float v_im = im_s[la];
    int c0 = q * 4;
    float4 v;
    v.x = (lb == c0 + 0) ? v_im : 0.0f;
    v.y = (lb == c0 + 1) ? v_im : 0.0f;
    v.z = (lb == c0 + 2) ? v_im : 0.0f;
    v.w = (lb == c0 + 3) ? v_im : 0.0f;
    out_sco4[base + k] = v;
  }
}

extern "C" void kernel_launch(void* const* d_in, const int* in_sizes, int n_in,
                              void* d_out, int out_size, void* d_ws, size_t ws_size,
                              hipStream_t stream) {
  const float* anchors = (const float*)d_in[0];
  // d_in[1] = num_anchors_list (compile-time constants here)
  const int* labels = (const int*)d_in[2];
  const float* gt_boxes = (const float*)d_in[3];
  const float* mask_gt = (const float*)d_in[4];
  const float* pred = (const float*)d_in[5];

  float* out = (float*)d_out;
  float* out_lab = out;                                    // 32*8400
  float* out_box = out + (size_t)BSZ * NA_TOTAL;           // 32*8400*4
  float* out_sco = out + (size_t)BSZ * NA_TOTAL * 5;       // 32*8400*80
  float* out_fgm = out + (size_t)BSZ * NA_TOTAL * 85;      // 32*8400

  int* pos_list = (int*)d_ws;  // 32*64*27 ints = 221 KB; fully overwritten each call

  // one wave per (b,g): 2048 waves, 4 waves (256 thr) per block
  stage1_kernel<<<(BSZ * NMAX) / 4, 256, 0, stream>>>(anchors, gt_boxes, mask_gt,
                                                      pos_list);

  dim3 g2((NA_TOTAL + 255) / 256, BSZ);
  stage2_kernel<<<g2, 256, 0, stream>>>(anchors, gt_boxes, labels, pred, pos_list,
                                        out_lab, out_box, (float4*)out_sco, out_fgm);
}